// Round 2
// baseline (676.124 us; speedup 1.0000x reference)
//
#include <hip/hip_runtime.h>
#include <math.h>

#define N_NODES 50000
#define E_EDGES 800000
#define D_IN    256
#define D_H     128
#define D_OUT   128

#define NPB     32                    // nodes per GEMM block
#define NBLK_FC ((N_NODES + NPB - 1) / NPB)   // 1563
#define SCAN_B  1024
#define NB_SCAN ((N_NODES + SCAN_B - 1) / SCAN_B)  // 49

// ---------------- K1: h = relu(x @ W_fc^T + b_fc) ----------------
// block: 256 thr, covers 32 nodes x 128 feats. Each thread: 2 feats x 8 nodes.
__global__ __launch_bounds__(256) void k_fc(const float* __restrict__ x,
                                            const float* __restrict__ W,
                                            const float* __restrict__ b,
                                            float* __restrict__ h) {
    __shared__ float xs[NPB * D_IN];            // 32 KB
    const int tid = threadIdx.x;
    const int node0 = blockIdx.x * NPB;

    // stage x tile: 32*256 floats = 2048 float4; 8 per thread, coalesced
    for (int i = 0; i < 8; ++i) {
        int idx = tid + i * 256;                // float4 index in tile
        int row = idx >> 6;                     // 64 float4 per row
        int col = idx & 63;
        float4 val = make_float4(0.f, 0.f, 0.f, 0.f);
        int gn = node0 + row;
        if (gn < N_NODES) val = ((const float4*)x)[(size_t)gn * 64 + col];
        ((float4*)xs)[idx] = val;
    }
    __syncthreads();

    const int j0 = (tid & 63) * 2;              // feature pair
    const int nbase = (tid >> 6) * 8;           // node group (wave-uniform)
    float acc0[8], acc1[8];
    const float b0 = b[j0], b1 = b[j0 + 1];
#pragma unroll
    for (int n = 0; n < 8; ++n) { acc0[n] = b0; acc1[n] = b1; }

    const float4* w0p = (const float4*)(W + (size_t)j0 * D_IN);
    const float4* w1p = (const float4*)(W + (size_t)(j0 + 1) * D_IN);
    for (int kk = 0; kk < D_IN / 4; ++kk) {
        float4 w0 = w0p[kk];
        float4 w1 = w1p[kk];
#pragma unroll
        for (int n = 0; n < 8; ++n) {
            float4 xv = ((const float4*)xs)[(nbase + n) * 64 + kk]; // wave broadcast
            acc0[n] += w0.x * xv.x + w0.y * xv.y + w0.z * xv.z + w0.w * xv.w;
            acc1[n] += w1.x * xv.x + w1.y * xv.y + w1.z * xv.z + w1.w * xv.w;
        }
    }
#pragma unroll
    for (int n = 0; n < 8; ++n) {
        int gn = node0 + nbase + n;
        if (gn < N_NODES) {
            float2 o;
            o.x = fmaxf(acc0[n], 0.f);
            o.y = fmaxf(acc1[n], 0.f);
            ((float2*)(h + (size_t)gn * D_H))[j0 >> 1] = o;
        }
    }
}

// ---------------- K2: q/k/v/skip = h @ W^T + b (blockIdx.y selects) --------
__global__ __launch_bounds__(256) void k_qkvs(const float* __restrict__ h,
                                              const float* __restrict__ Wq, const float* __restrict__ bq,
                                              const float* __restrict__ Wk, const float* __restrict__ bk,
                                              const float* __restrict__ Wv, const float* __restrict__ bv,
                                              const float* __restrict__ Ws, const float* __restrict__ bs,
                                              float* __restrict__ qo, float* __restrict__ ko,
                                              float* __restrict__ vo, float* __restrict__ so) {
    const float* W; const float* b; float* dst;
    switch (blockIdx.y) {
        case 0:  W = Wq; b = bq; dst = qo; break;
        case 1:  W = Wk; b = bk; dst = ko; break;
        case 2:  W = Wv; b = bv; dst = vo; break;
        default: W = Ws; b = bs; dst = so; break;
    }
    __shared__ float hs[NPB * D_H];             // 16 KB
    const int tid = threadIdx.x;
    const int node0 = blockIdx.x * NPB;

    // stage h tile: 32*128 floats = 1024 float4; 4 per thread
    for (int i = 0; i < 4; ++i) {
        int idx = tid + i * 256;
        int row = idx >> 5;                     // 32 float4 per row
        int col = idx & 31;
        float4 val = make_float4(0.f, 0.f, 0.f, 0.f);
        int gn = node0 + row;
        if (gn < N_NODES) val = ((const float4*)h)[(size_t)gn * 32 + col];
        ((float4*)hs)[idx] = val;
    }
    __syncthreads();

    const int j0 = (tid & 63) * 2;
    const int nbase = (tid >> 6) * 8;
    float acc0[8], acc1[8];
    const float b0 = b[j0], b1 = b[j0 + 1];
#pragma unroll
    for (int n = 0; n < 8; ++n) { acc0[n] = b0; acc1[n] = b1; }

    const float4* w0p = (const float4*)(W + (size_t)j0 * D_H);
    const float4* w1p = (const float4*)(W + (size_t)(j0 + 1) * D_H);
    for (int kk = 0; kk < D_H / 4; ++kk) {
        float4 w0 = w0p[kk];
        float4 w1 = w1p[kk];
#pragma unroll
        for (int n = 0; n < 8; ++n) {
            float4 xv = ((const float4*)hs)[(nbase + n) * 32 + kk];
            acc0[n] += w0.x * xv.x + w0.y * xv.y + w0.z * xv.z + w0.w * xv.w;
            acc1[n] += w1.x * xv.x + w1.y * xv.y + w1.z * xv.z + w1.w * xv.w;
        }
    }
#pragma unroll
    for (int n = 0; n < 8; ++n) {
        int gn = node0 + nbase + n;
        if (gn < N_NODES) {
            float2 o; o.x = acc0[n]; o.y = acc1[n];
            ((float2*)(dst + (size_t)gn * D_OUT))[j0 >> 1] = o;
        }
    }
}

// ---------------- CSR build ----------------
__global__ void k_deg(const int* __restrict__ ei, int* __restrict__ deg) {
    int e = blockIdx.x * 256 + threadIdx.x;
    if (e < E_EDGES) atomicAdd(&deg[ei[E_EDGES + e]], 1);
}

__global__ __launch_bounds__(SCAN_B) void k_scan1(const int* __restrict__ deg,
                                                  int* __restrict__ offs,
                                                  int* __restrict__ bsums) {
    __shared__ int s[SCAN_B];
    int tid = threadIdx.x;
    int gid = blockIdx.x * SCAN_B + tid;
    int val = (gid < N_NODES) ? deg[gid] : 0;
    s[tid] = val;
    __syncthreads();
    for (int off = 1; off < SCAN_B; off <<= 1) {
        int t = (tid >= off) ? s[tid - off] : 0;
        __syncthreads();
        s[tid] += t;
        __syncthreads();
    }
    int incl = s[tid];
    if (gid < N_NODES) offs[gid] = incl - val;      // exclusive
    if (tid == SCAN_B - 1) bsums[blockIdx.x] = incl;
}

__global__ void k_scan2(const int* __restrict__ bsums, int* __restrict__ bpref) {
    if (threadIdx.x == 0 && blockIdx.x == 0) {
        int run = 0;
        for (int i = 0; i < NB_SCAN; ++i) { bpref[i] = run; run += bsums[i]; }
    }
}

__global__ __launch_bounds__(SCAN_B) void k_scan3(int* __restrict__ offs,
                                                  const int* __restrict__ bpref,
                                                  int* __restrict__ cursor) {
    int gid = blockIdx.x * SCAN_B + threadIdx.x;
    if (gid < N_NODES) {
        int o = offs[gid] + bpref[blockIdx.x];
        offs[gid] = o;
        cursor[gid] = o;
    }
    if (gid == 0) offs[N_NODES] = E_EDGES;
}

__global__ void k_fill(const int* __restrict__ ei, int* __restrict__ cursor,
                       int* __restrict__ ssrc) {
    int e = blockIdx.x * 256 + threadIdx.x;
    if (e < E_EDGES) {
        int d = ei[E_EDGES + e];
        int p = atomicAdd(&cursor[d], 1);
        ssrc[p] = ei[e];
    }
}

// ---------------- K6: per-node online-softmax aggregation ----------------
// one wave (64 lanes) per node; lane holds 2 feature channels.
__global__ __launch_bounds__(256) void k_agg(const float* __restrict__ q,
                                             const float* __restrict__ k,
                                             const float* __restrict__ v,
                                             const int* __restrict__ offs,
                                             const int* __restrict__ ssrc,
                                             float* __restrict__ out) {
    const int wave = threadIdx.x >> 6;
    const int lane = threadIdx.x & 63;
    const int node = blockIdx.x * 4 + wave;
    if (node >= N_NODES) return;
    const int beg = offs[node];
    const int end = offs[node + 1];
    if (beg == end) return;                       // out already holds skip

    float2 q2 = ((const float2*)(q + (size_t)node * D_OUT))[lane];
    float m = -INFINITY, l = 0.f;
    float2 acc = make_float2(0.f, 0.f);
    const float scale = 0.08838834764831845f;     // 1/sqrt(128)

    for (int p = beg; p < end; ++p) {
        int j = ssrc[p];
        float2 k2 = ((const float2*)(k + (size_t)j * D_OUT))[lane];
        float2 v2 = ((const float2*)(v + (size_t)j * D_OUT))[lane];
        float s = q2.x * k2.x + q2.y * k2.y;
#pragma unroll
        for (int off = 32; off > 0; off >>= 1) s += __shfl_xor(s, off, 64);
        s *= scale;
        float mn = fmaxf(m, s);
        float ea = __expf(m - mn);                // 0 on first iter (m=-inf)
        float es = __expf(s - mn);
        l = l * ea + es;
        acc.x = acc.x * ea + es * v2.x;
        acc.y = acc.y * ea + es * v2.y;
        m = mn;
    }
    float inv = 1.f / l;
    float2* o = (float2*)(out + (size_t)node * D_OUT);
    float2 cur = o[lane];
    cur.x += acc.x * inv;
    cur.y += acc.y * inv;
    o[lane] = cur;
}

// ---------------- host launch ----------------
extern "C" void kernel_launch(void* const* d_in, const int* in_sizes, int n_in,
                              void* d_out, int out_size, void* d_ws, size_t ws_size,
                              hipStream_t stream) {
    const float* x     = (const float*)d_in[0];
    const int*   ei    = (const int*)d_in[1];
    const float* W_fc  = (const float*)d_in[2];
    const float* b_fc  = (const float*)d_in[3];
    const float* W_q   = (const float*)d_in[4];
    const float* b_q   = (const float*)d_in[5];
    const float* W_k   = (const float*)d_in[6];
    const float* b_k   = (const float*)d_in[7];
    const float* W_v   = (const float*)d_in[8];
    const float* b_v   = (const float*)d_in[9];
    const float* W_s   = (const float*)d_in[10];
    const float* b_s   = (const float*)d_in[11];
    float* out = (float*)d_out;

    // Workspace layout — total EXACTLY 4 * N * 128 * 4 B = 102,400,000 B.
    // q, k, v live for the whole launch; h is dead after k_qkvs, so the CSR
    // arrays (3.8 MB) alias h's 25.6 MB region. NOTHING is placed past the
    // q+k+v+h footprint (prior round overran ws and corrupted the harness's
    // pristine input copies -> post-timing divergence).
    float* qb = (float*)d_ws;
    float* kb = qb + (size_t)N_NODES * D_OUT;
    float* vb = kb + (size_t)N_NODES * D_OUT;
    float* h  = vb + (size_t)N_NODES * D_OUT;

    int* deg    = (int*)h;                // aliases h; used only after k_qkvs
    int* offs   = deg + N_NODES;          // N+1 entries
    int* cursor = offs + (N_NODES + 1);
    int* bsums  = cursor + N_NODES;
    int* bpref  = bsums + 64;
    int* ssrc   = bpref + 64;             // E entries  (total ~3.8 MB << 25.6 MB)

    k_fc<<<NBLK_FC, 256, 0, stream>>>(x, W_fc, b_fc, h);
    k_qkvs<<<dim3(NBLK_FC, 4), 256, 0, stream>>>(h, W_q, b_q, W_k, b_k, W_v, b_v,
                                                 W_s, b_s, qb, kb, vb, out);
    // h is dead from here; CSR arrays may now clobber its region.
    hipMemsetAsync(deg, 0, N_NODES * sizeof(int), stream);
    k_deg<<<(E_EDGES + 255) / 256, 256, 0, stream>>>(ei, deg);
    k_scan1<<<NB_SCAN, SCAN_B, 0, stream>>>(deg, offs, bsums);
    k_scan2<<<1, 64, 0, stream>>>(bsums, bpref);
    k_scan3<<<NB_SCAN, SCAN_B, 0, stream>>>(offs, bpref, cursor);
    k_fill<<<(E_EDGES + 255) / 256, 256, 0, stream>>>(ei, cursor, ssrc);
    k_agg<<<(N_NODES + 3) / 4, 256, 0, stream>>>(qb, kb, vb, offs, ssrc, out);
}

// Round 3
// 403.243 us; speedup vs baseline: 1.6767x; 1.6767x over previous
//
#include <hip/hip_runtime.h>
#include <math.h>

#define N_NODES 50000
#define E_EDGES 800000
#define D_IN    256
#define D_H     128
#define D_OUT   128

#define MT   64                     // nodes per GEMM block
#define KC   64                     // K chunk staged in LDS
#define LDA  72                     // padded LDS row stride (bf16 elems)
#define NBLK ((N_NODES + MT - 1) / MT)   // 782
#define SCAN_B  1024
#define NB_SCAN ((N_NODES + SCAN_B - 1) / SCAN_B)  // 49

typedef __attribute__((ext_vector_type(8))) short bf16x8;
typedef __attribute__((ext_vector_type(4))) float f32x4;

__device__ __forceinline__ unsigned short f2bf(float f) {
    unsigned u = __float_as_uint(f);
    return (unsigned short)((u + 0x7FFFu + ((u >> 16) & 1u)) >> 16);
}

// ---------------- K1: h = relu(x @ W_fc^T + b_fc), h stored bf16 ----------
// 256 thr = 4 waves; block tile 64 nodes x 128 feats; wave = 64 nodes x 32 feats.
__global__ __launch_bounds__(256) void k_fc(const float* __restrict__ x,
                                            const float* __restrict__ W,
                                            const float* __restrict__ b,
                                            unsigned short* __restrict__ h) {
    __shared__ __align__(16) unsigned short As[MT * LDA];    // 9216 B
    __shared__ __align__(16) unsigned short Ws[D_H * LDA];   // 18432 B
    const int tid  = threadIdx.x;
    const int lane = tid & 63;
    const int wid  = tid >> 6;
    const int lm   = lane & 15;
    const int quad = lane >> 4;
    const int node0 = blockIdx.x * MT;

    f32x4 acc[4][2];
#pragma unroll
    for (int i = 0; i < 4; ++i)
#pragma unroll
        for (int j = 0; j < 2; ++j) { acc[i][j][0]=0.f; acc[i][j][1]=0.f; acc[i][j][2]=0.f; acc[i][j][3]=0.f; }

    for (int kc = 0; kc < D_IN; kc += KC) {
        // stage A tile: 64 nodes x 64 k, fp32 -> bf16 (coalesced float4 reads)
#pragma unroll
        for (int i = 0; i < 4; ++i) {
            int idx = tid + i * 256;
            int row = idx >> 4;            // 16 float4 per row
            int kq  = idx & 15;
            int gn  = node0 + row;
            float4 v = make_float4(0.f, 0.f, 0.f, 0.f);
            if (gn < N_NODES) v = *(const float4*)(x + (size_t)gn * D_IN + kc + kq * 4);
            unsigned r0 = (unsigned)f2bf(v.x) | ((unsigned)f2bf(v.y) << 16);
            unsigned r1 = (unsigned)f2bf(v.z) | ((unsigned)f2bf(v.w) << 16);
            *(uint2*)&As[row * LDA + kq * 4] = make_uint2(r0, r1);
        }
        // stage W tile: 128 feats x 64 k
#pragma unroll
        for (int i = 0; i < 8; ++i) {
            int idx = tid + i * 256;
            int row = idx >> 4;
            int kq  = idx & 15;
            float4 v = *(const float4*)(W + (size_t)row * D_IN + kc + kq * 4);
            unsigned r0 = (unsigned)f2bf(v.x) | ((unsigned)f2bf(v.y) << 16);
            unsigned r1 = (unsigned)f2bf(v.z) | ((unsigned)f2bf(v.w) << 16);
            *(uint2*)&Ws[row * LDA + kq * 4] = make_uint2(r0, r1);
        }
        __syncthreads();
#pragma unroll
        for (int ks = 0; ks < KC; ks += 32) {
            bf16x8 af[4], bfr[2];
#pragma unroll
            for (int nt = 0; nt < 4; ++nt)
                af[nt] = *(const bf16x8*)&As[(nt * 16 + lm) * LDA + ks + quad * 8];
#pragma unroll
            for (int ft = 0; ft < 2; ++ft)
                bfr[ft] = *(const bf16x8*)&Ws[(wid * 32 + ft * 16 + lm) * LDA + ks + quad * 8];
#pragma unroll
            for (int nt = 0; nt < 4; ++nt)
#pragma unroll
                for (int ft = 0; ft < 2; ++ft)
                    acc[nt][ft] = __builtin_amdgcn_mfma_f32_16x16x32_bf16(af[nt], bfr[ft], acc[nt][ft], 0, 0, 0);
        }
        __syncthreads();
    }
    // epilogue: + bias, relu, store bf16
#pragma unroll
    for (int ft = 0; ft < 2; ++ft) {
        int feat = wid * 32 + ft * 16 + lm;         // C/D col = lane&15
        float bb = b[feat];
#pragma unroll
        for (int nt = 0; nt < 4; ++nt)
#pragma unroll
            for (int r = 0; r < 4; ++r) {           // C/D row = quad*4 + r
                int gn = node0 + nt * 16 + quad * 4 + r;
                if (gn < N_NODES) {
                    float vv = fmaxf(acc[nt][ft][r] + bb, 0.f);
                    h[(size_t)gn * D_H + feat] = f2bf(vv);
                }
            }
    }
}

// ---------------- K2: q/k/v/skip = h @ W^T + b, blockIdx.y selects --------
__global__ __launch_bounds__(256) void k_qkvs(const unsigned short* __restrict__ h,
                                              const float* __restrict__ Wq, const float* __restrict__ bq,
                                              const float* __restrict__ Wk, const float* __restrict__ bk,
                                              const float* __restrict__ Wv, const float* __restrict__ bv,
                                              const float* __restrict__ Wsk, const float* __restrict__ bsk,
                                              float* __restrict__ qo, float* __restrict__ ko,
                                              float* __restrict__ vo, float* __restrict__ so) {
    const float* W; const float* b; float* dst;
    switch (blockIdx.y) {
        case 0:  W = Wq;  b = bq;  dst = qo; break;
        case 1:  W = Wk;  b = bk;  dst = ko; break;
        case 2:  W = Wv;  b = bv;  dst = vo; break;
        default: W = Wsk; b = bsk; dst = so; break;
    }
    __shared__ __align__(16) unsigned short As[MT * LDA];
    __shared__ __align__(16) unsigned short Ws[D_OUT * LDA];
    const int tid  = threadIdx.x;
    const int lane = tid & 63;
    const int wid  = tid >> 6;
    const int lm   = lane & 15;
    const int quad = lane >> 4;
    const int node0 = blockIdx.x * MT;

    f32x4 acc[4][2];
#pragma unroll
    for (int i = 0; i < 4; ++i)
#pragma unroll
        for (int j = 0; j < 2; ++j) { acc[i][j][0]=0.f; acc[i][j][1]=0.f; acc[i][j][2]=0.f; acc[i][j][3]=0.f; }

    for (int kc = 0; kc < D_H; kc += KC) {
        // stage A tile: 64 nodes x 64 k bf16, direct 16B copies
#pragma unroll
        for (int i = 0; i < 2; ++i) {
            int idx = tid + i * 256;
            int row = idx >> 3;            // 8 x (8-elem groups) per row
            int kq  = idx & 7;
            int gn  = node0 + row;
            uint4 v = make_uint4(0u, 0u, 0u, 0u);
            if (gn < N_NODES) v = *(const uint4*)(h + (size_t)gn * D_H + kc + kq * 8);
            *(uint4*)&As[row * LDA + kq * 8] = v;
        }
        // stage W tile: 128 feats x 64 k fp32 -> bf16
#pragma unroll
        for (int i = 0; i < 8; ++i) {
            int idx = tid + i * 256;
            int row = idx >> 4;
            int kq  = idx & 15;
            float4 v = *(const float4*)(W + (size_t)row * D_H + kc + kq * 4);
            unsigned r0 = (unsigned)f2bf(v.x) | ((unsigned)f2bf(v.y) << 16);
            unsigned r1 = (unsigned)f2bf(v.z) | ((unsigned)f2bf(v.w) << 16);
            *(uint2*)&Ws[row * LDA + kq * 4] = make_uint2(r0, r1);
        }
        __syncthreads();
#pragma unroll
        for (int ks = 0; ks < KC; ks += 32) {
            bf16x8 af[4], bfr[2];
#pragma unroll
            for (int nt = 0; nt < 4; ++nt)
                af[nt] = *(const bf16x8*)&As[(nt * 16 + lm) * LDA + ks + quad * 8];
#pragma unroll
            for (int ft = 0; ft < 2; ++ft)
                bfr[ft] = *(const bf16x8*)&Ws[(wid * 32 + ft * 16 + lm) * LDA + ks + quad * 8];
#pragma unroll
            for (int nt = 0; nt < 4; ++nt)
#pragma unroll
                for (int ft = 0; ft < 2; ++ft)
                    acc[nt][ft] = __builtin_amdgcn_mfma_f32_16x16x32_bf16(af[nt], bfr[ft], acc[nt][ft], 0, 0, 0);
        }
        __syncthreads();
    }
#pragma unroll
    for (int ft = 0; ft < 2; ++ft) {
        int feat = wid * 32 + ft * 16 + lm;
        float bb = b[feat];
#pragma unroll
        for (int nt = 0; nt < 4; ++nt)
#pragma unroll
            for (int r = 0; r < 4; ++r) {
                int gn = node0 + nt * 16 + quad * 4 + r;
                if (gn < N_NODES)
                    dst[(size_t)gn * D_OUT + feat] = acc[nt][ft][r] + bb;
            }
    }
}

// ---------------- CSR build ----------------
__global__ void k_deg(const int* __restrict__ ei, int* __restrict__ deg) {
    int e = blockIdx.x * 256 + threadIdx.x;
    if (e < E_EDGES) atomicAdd(&deg[ei[E_EDGES + e]], 1);
}

__global__ __launch_bounds__(SCAN_B) void k_scan1(const int* __restrict__ deg,
                                                  int* __restrict__ offs,
                                                  int* __restrict__ bsums) {
    __shared__ int s[SCAN_B];
    int tid = threadIdx.x;
    int gid = blockIdx.x * SCAN_B + tid;
    int val = (gid < N_NODES) ? deg[gid] : 0;
    s[tid] = val;
    __syncthreads();
    for (int off = 1; off < SCAN_B; off <<= 1) {
        int t = (tid >= off) ? s[tid - off] : 0;
        __syncthreads();
        s[tid] += t;
        __syncthreads();
    }
    int incl = s[tid];
    if (gid < N_NODES) offs[gid] = incl - val;      // exclusive
    if (tid == SCAN_B - 1) bsums[blockIdx.x] = incl;
}

__global__ void k_scan2(const int* __restrict__ bsums, int* __restrict__ bpref) {
    if (threadIdx.x == 0 && blockIdx.x == 0) {
        int run = 0;
        for (int i = 0; i < NB_SCAN; ++i) { bpref[i] = run; run += bsums[i]; }
    }
}

__global__ __launch_bounds__(SCAN_B) void k_scan3(int* __restrict__ offs,
                                                  const int* __restrict__ bpref,
                                                  int* __restrict__ cursor) {
    int gid = blockIdx.x * SCAN_B + threadIdx.x;
    if (gid < N_NODES) {
        int o = offs[gid] + bpref[blockIdx.x];
        offs[gid] = o;
        cursor[gid] = o;
    }
    if (gid == 0) offs[N_NODES] = E_EDGES;
}

__global__ void k_fill(const int* __restrict__ ei, int* __restrict__ cursor,
                       int* __restrict__ ssrc) {
    int e = blockIdx.x * 256 + threadIdx.x;
    if (e < E_EDGES) {
        int d = ei[E_EDGES + e];
        int p = atomicAdd(&cursor[d], 1);
        ssrc[p] = ei[e];
    }
}

// ---------------- K6: per-node online-softmax aggregation ----------------
__global__ __launch_bounds__(256) void k_agg(const float* __restrict__ q,
                                             const float* __restrict__ k,
                                             const float* __restrict__ v,
                                             const int* __restrict__ offs,
                                             const int* __restrict__ ssrc,
                                             float* __restrict__ out) {
    const int wave = threadIdx.x >> 6;
    const int lane = threadIdx.x & 63;
    const int node = blockIdx.x * 4 + wave;
    if (node >= N_NODES) return;
    const int beg = offs[node];
    const int end = offs[node + 1];
    if (beg == end) return;                       // out already holds skip

    float2 q2 = ((const float2*)(q + (size_t)node * D_OUT))[lane];
    float m = -INFINITY, l = 0.f;
    float2 acc = make_float2(0.f, 0.f);
    const float scale = 0.08838834764831845f;     // 1/sqrt(128)

    for (int p = beg; p < end; ++p) {
        int j = ssrc[p];
        float2 k2 = ((const float2*)(k + (size_t)j * D_OUT))[lane];
        float2 v2 = ((const float2*)(v + (size_t)j * D_OUT))[lane];
        float s = q2.x * k2.x + q2.y * k2.y;
#pragma unroll
        for (int off = 32; off > 0; off >>= 1) s += __shfl_xor(s, off, 64);
        s *= scale;
        float mn = fmaxf(m, s);
        float ea = __expf(m - mn);
        float es = __expf(s - mn);
        l = l * ea + es;
        acc.x = acc.x * ea + es * v2.x;
        acc.y = acc.y * ea + es * v2.y;
        m = mn;
    }
    float inv = 1.f / l;
    float2* o = (float2*)(out + (size_t)node * D_OUT);
    float2 cur = o[lane];
    cur.x += acc.x * inv;
    cur.y += acc.y * inv;
    o[lane] = cur;
}

// ---------------- host launch ----------------
extern "C" void kernel_launch(void* const* d_in, const int* in_sizes, int n_in,
                              void* d_out, int out_size, void* d_ws, size_t ws_size,
                              hipStream_t stream) {
    const float* x     = (const float*)d_in[0];
    const int*   ei    = (const int*)d_in[1];
    const float* W_fc  = (const float*)d_in[2];
    const float* b_fc  = (const float*)d_in[3];
    const float* W_q   = (const float*)d_in[4];
    const float* b_q   = (const float*)d_in[5];
    const float* W_k   = (const float*)d_in[6];
    const float* b_k   = (const float*)d_in[7];
    const float* W_v   = (const float*)d_in[8];
    const float* b_v   = (const float*)d_in[9];
    const float* W_s   = (const float*)d_in[10];
    const float* b_s   = (const float*)d_in[11];
    float* out = (float*)d_out;

    // Workspace layout (ws_size >= 102.4 MB):
    //   qb, kb, vb fp32 (3 x 25.6 MB) | h bf16 (12.8 MB) | CSR (~3.8 MB)
    // total 93.8 MB — stays inside the 102.4 MB reference footprint.
    float* qb = (float*)d_ws;
    float* kb = qb + (size_t)N_NODES * D_OUT;
    float* vb = kb + (size_t)N_NODES * D_OUT;
    unsigned short* hb = (unsigned short*)(vb + (size_t)N_NODES * D_OUT);
    int* deg    = (int*)(hb + (size_t)N_NODES * D_H);
    int* offs   = deg + N_NODES;          // N+1 entries
    int* cursor = offs + (N_NODES + 1);
    int* bsums  = cursor + N_NODES;
    int* bpref  = bsums + 64;
    int* ssrc   = bpref + 64;             // E entries

    hipMemsetAsync(deg, 0, N_NODES * sizeof(int), stream);

    k_fc<<<NBLK, 256, 0, stream>>>(x, W_fc, b_fc, hb);
    k_qkvs<<<dim3(NBLK, 4), 256, 0, stream>>>(hb, W_q, b_q, W_k, b_k, W_v, b_v,
                                              W_s, b_s, qb, kb, vb, out);
    k_deg<<<(E_EDGES + 255) / 256, 256, 0, stream>>>(ei, deg);
    k_scan1<<<NB_SCAN, SCAN_B, 0, stream>>>(deg, offs, bsums);
    k_scan2<<<1, 64, 0, stream>>>(bsums, bpref);
    k_scan3<<<NB_SCAN, SCAN_B, 0, stream>>>(offs, bpref, cursor);
    k_fill<<<(E_EDGES + 255) / 256, 256, 0, stream>>>(ei, cursor, ssrc);
    k_agg<<<(N_NODES + 3) / 4, 256, 0, stream>>>(qb, kb, vb, offs, ssrc, out);
}

// Round 4
// 379.806 us; speedup vs baseline: 1.7802x; 1.0617x over previous
//
#include <hip/hip_runtime.h>
#include <math.h>

#define N_NODES 50000
#define E_EDGES 800000
#define D_IN    256
#define D_H     128
#define D_OUT   128

#define MT    64                    // nodes per GEMM block
#define KC    64                    // phase-1 K chunk
#define LDA1  72                    // phase-1 LDS row stride (bf16 elems)
#define LDA2  136                   // phase-2 LDS row stride (bf16 elems), 16B-aligned
#define NBLK  ((N_NODES + MT - 1) / MT)   // 782
#define SCAN_B  1024
#define NB_SCAN ((N_NODES + SCAN_B - 1) / SCAN_B)  // 49

typedef __attribute__((ext_vector_type(8))) short bf16x8;
typedef __attribute__((ext_vector_type(4))) float f32x4;

__device__ __forceinline__ unsigned short f2bf(float f) {
    unsigned u = __float_as_uint(f);
    return (unsigned short)((u + 0x7FFFu + ((u >> 16) & 1u)) >> 16);
}
__device__ __forceinline__ float bf2f(unsigned short u) {
    return __uint_as_float((unsigned)u << 16);
}

// ---------------- K1 (fused): h = relu(x@W_fc^T+b) in LDS, then
//                  q = h@Wq^T+bq (fp32), kv = bf16[k|v] interleaved,
//                  out = h@Wsk^T+bsk (skip, fp32)
__global__ __launch_bounds__(256) void k_fused(const float* __restrict__ x,
                                               const float* __restrict__ W_fc, const float* __restrict__ b_fc,
                                               const float* __restrict__ W_q,  const float* __restrict__ b_q,
                                               const float* __restrict__ W_k,  const float* __restrict__ b_k,
                                               const float* __restrict__ W_v,  const float* __restrict__ b_v,
                                               const float* __restrict__ W_s,  const float* __restrict__ b_s,
                                               float* __restrict__ qo,
                                               unsigned short* __restrict__ kv,
                                               float* __restrict__ out) {
    // LDS: Wst region (128*136 shorts = 34.8KB) aliased by phase-1 As+Ws1;
    //      hs (64*136 shorts = 17.4KB) holds bf16 h tile. Total 52.2 KB.
    __shared__ __align__(16) unsigned short smem[128 * LDA2 + MT * LDA2];
    unsigned short* Wst = smem;                  // phase-2 W chunk (stride LDA2)
    unsigned short* As  = smem;                  // phase-1 A tile  (stride LDA1)
    unsigned short* Ws1 = smem + MT * LDA1;      // phase-1 W chunk (stride LDA1)
    unsigned short* hs  = smem + 128 * LDA2;     // h tile (stride LDA2)

    const int tid  = threadIdx.x;
    const int lane = tid & 63;
    const int wid  = tid >> 6;
    const int lm   = lane & 15;
    const int quad = lane >> 4;
    const int node0 = blockIdx.x * MT;

    // ---------- phase 1: h tile ----------
    f32x4 acc[4][2];
#pragma unroll
    for (int i = 0; i < 4; ++i)
#pragma unroll
        for (int j = 0; j < 2; ++j) { acc[i][j][0]=0.f; acc[i][j][1]=0.f; acc[i][j][2]=0.f; acc[i][j][3]=0.f; }

    for (int kc = 0; kc < D_IN; kc += KC) {
#pragma unroll
        for (int i = 0; i < 4; ++i) {            // A: 64 nodes x 64 k
            int idx = tid + i * 256;
            int row = idx >> 4;
            int kq  = idx & 15;
            int gn  = node0 + row;
            float4 v = make_float4(0.f, 0.f, 0.f, 0.f);
            if (gn < N_NODES) v = *(const float4*)(x + (size_t)gn * D_IN + kc + kq * 4);
            unsigned r0 = (unsigned)f2bf(v.x) | ((unsigned)f2bf(v.y) << 16);
            unsigned r1 = (unsigned)f2bf(v.z) | ((unsigned)f2bf(v.w) << 16);
            *(uint2*)&As[row * LDA1 + kq * 4] = make_uint2(r0, r1);
        }
#pragma unroll
        for (int i = 0; i < 8; ++i) {            // W_fc: 128 feats x 64 k
            int idx = tid + i * 256;
            int row = idx >> 4;
            int kq  = idx & 15;
            float4 v = *(const float4*)(W_fc + (size_t)row * D_IN + kc + kq * 4);
            unsigned r0 = (unsigned)f2bf(v.x) | ((unsigned)f2bf(v.y) << 16);
            unsigned r1 = (unsigned)f2bf(v.z) | ((unsigned)f2bf(v.w) << 16);
            *(uint2*)&Ws1[row * LDA1 + kq * 4] = make_uint2(r0, r1);
        }
        __syncthreads();
#pragma unroll
        for (int ks = 0; ks < KC; ks += 32) {
            bf16x8 af[4], bfr[2];
#pragma unroll
            for (int nt = 0; nt < 4; ++nt)
                af[nt] = *(const bf16x8*)&As[(nt * 16 + lm) * LDA1 + ks + quad * 8];
#pragma unroll
            for (int ft = 0; ft < 2; ++ft)
                bfr[ft] = *(const bf16x8*)&Ws1[(wid * 32 + ft * 16 + lm) * LDA1 + ks + quad * 8];
#pragma unroll
            for (int nt = 0; nt < 4; ++nt)
#pragma unroll
                for (int ft = 0; ft < 2; ++ft)
                    acc[nt][ft] = __builtin_amdgcn_mfma_f32_16x16x32_bf16(af[nt], bfr[ft], acc[nt][ft], 0, 0, 0);
        }
        __syncthreads();
    }
    // epilogue: bias+relu -> hs (bf16), LDS only
#pragma unroll
    for (int ft = 0; ft < 2; ++ft) {
        int feat = wid * 32 + ft * 16 + lm;
        float bb = b_fc[feat];
#pragma unroll
        for (int nt = 0; nt < 4; ++nt)
#pragma unroll
            for (int r = 0; r < 4; ++r) {
                int lrow = nt * 16 + quad * 4 + r;
                hs[lrow * LDA2 + feat] = f2bf(fmaxf(acc[nt][ft][r] + bb, 0.f));
            }
    }
    __syncthreads();

    // ---------- phase 2: q / k / v / skip ----------
    for (int sel = 0; sel < 4; ++sel) {
        const float* W; const float* b;
        switch (sel) {
            case 0:  W = W_q; b = b_q; break;
            case 1:  W = W_k; b = b_k; break;
            case 2:  W = W_v; b = b_v; break;
            default: W = W_s; b = b_s; break;
        }
        // stage full 128x128 W chunk as bf16
#pragma unroll
        for (int i = 0; i < 16; ++i) {
            int idx = tid + i * 256;             // float4 groups: 4096
            int row = idx >> 5;                  // 32 per row
            int kq  = idx & 31;
            float4 v = *(const float4*)(W + (size_t)row * D_H + kq * 4);
            unsigned r0 = (unsigned)f2bf(v.x) | ((unsigned)f2bf(v.y) << 16);
            unsigned r1 = (unsigned)f2bf(v.z) | ((unsigned)f2bf(v.w) << 16);
            *(uint2*)&Wst[row * LDA2 + kq * 4] = make_uint2(r0, r1);
        }
        __syncthreads();

        f32x4 a2[4][2];
#pragma unroll
        for (int i = 0; i < 4; ++i)
#pragma unroll
            for (int j = 0; j < 2; ++j) { a2[i][j][0]=0.f; a2[i][j][1]=0.f; a2[i][j][2]=0.f; a2[i][j][3]=0.f; }
#pragma unroll
        for (int ks = 0; ks < D_H; ks += 32) {
            bf16x8 af[4], bfr[2];
#pragma unroll
            for (int nt = 0; nt < 4; ++nt)
                af[nt] = *(const bf16x8*)&hs[(nt * 16 + lm) * LDA2 + ks + quad * 8];
#pragma unroll
            for (int ft = 0; ft < 2; ++ft)
                bfr[ft] = *(const bf16x8*)&Wst[(wid * 32 + ft * 16 + lm) * LDA2 + ks + quad * 8];
#pragma unroll
            for (int nt = 0; nt < 4; ++nt)
#pragma unroll
                for (int ft = 0; ft < 2; ++ft)
                    a2[nt][ft] = __builtin_amdgcn_mfma_f32_16x16x32_bf16(af[nt], bfr[ft], a2[nt][ft], 0, 0, 0);
        }
        // epilogue
#pragma unroll
        for (int ft = 0; ft < 2; ++ft) {
            int feat = wid * 32 + ft * 16 + lm;
            float bb = b[feat];
#pragma unroll
            for (int nt = 0; nt < 4; ++nt)
#pragma unroll
                for (int r = 0; r < 4; ++r) {
                    int gn = node0 + nt * 16 + quad * 4 + r;
                    if (gn < N_NODES) {
                        float vv = a2[nt][ft][r] + bb;
                        if (sel == 0)      qo[(size_t)gn * D_OUT + feat] = vv;
                        else if (sel == 1) kv[(size_t)gn * 256 + feat] = f2bf(vv);
                        else if (sel == 2) kv[(size_t)gn * 256 + 128 + feat] = f2bf(vv);
                        else               out[(size_t)gn * D_OUT + feat] = vv;
                    }
                }
        }
        __syncthreads();                          // Wst reads done before restage
    }
}

// ---------------- CSR build ----------------
__global__ void k_deg(const int* __restrict__ ei, int* __restrict__ deg) {
    int e = blockIdx.x * 256 + threadIdx.x;
    if (e < E_EDGES) atomicAdd(&deg[ei[E_EDGES + e]], 1);
}

__global__ __launch_bounds__(SCAN_B) void k_scan1(const int* __restrict__ deg,
                                                  int* __restrict__ offs,
                                                  int* __restrict__ bsums) {
    __shared__ int s[SCAN_B];
    int tid = threadIdx.x;
    int gid = blockIdx.x * SCAN_B + tid;
    int val = (gid < N_NODES) ? deg[gid] : 0;
    s[tid] = val;
    __syncthreads();
    for (int off = 1; off < SCAN_B; off <<= 1) {
        int t = (tid >= off) ? s[tid - off] : 0;
        __syncthreads();
        s[tid] += t;
        __syncthreads();
    }
    int incl = s[tid];
    if (gid < N_NODES) offs[gid] = incl - val;      // exclusive
    if (tid == SCAN_B - 1) bsums[blockIdx.x] = incl;
}

__global__ void k_scan2(const int* __restrict__ bsums, int* __restrict__ bpref) {
    if (threadIdx.x == 0 && blockIdx.x == 0) {
        int run = 0;
        for (int i = 0; i < NB_SCAN; ++i) { bpref[i] = run; run += bsums[i]; }
    }
}

__global__ __launch_bounds__(SCAN_B) void k_scan3(int* __restrict__ offs,
                                                  const int* __restrict__ bpref,
                                                  int* __restrict__ cursor) {
    int gid = blockIdx.x * SCAN_B + threadIdx.x;
    if (gid < N_NODES) {
        int o = offs[gid] + bpref[blockIdx.x];
        offs[gid] = o;
        cursor[gid] = o;
    }
    if (gid == 0) offs[N_NODES] = E_EDGES;
}

__global__ void k_fill(const int* __restrict__ ei, int* __restrict__ cursor,
                       int* __restrict__ ssrc) {
    int e = blockIdx.x * 256 + threadIdx.x;
    if (e < E_EDGES) {
        int d = ei[E_EDGES + e];
        int p = atomicAdd(&cursor[d], 1);
        ssrc[p] = ei[e];
    }
}

// ---------------- K6: per-node online-softmax aggregation (bf16 kv) -------
// one wave per node; lane holds 2 feature channels; 2-edge ILP per iter.
__global__ __launch_bounds__(256) void k_agg(const float* __restrict__ q,
                                             const unsigned short* __restrict__ kv,
                                             const int* __restrict__ offs,
                                             const int* __restrict__ ssrc,
                                             float* __restrict__ out) {
    const int wave = threadIdx.x >> 6;
    const int lane = threadIdx.x & 63;
    const int node = blockIdx.x * 4 + wave;
    if (node >= N_NODES) return;
    const int beg = offs[node];
    const int end = offs[node + 1];
    if (beg == end) return;                       // out already holds skip

    float2 q2 = ((const float2*)(q + (size_t)node * D_OUT))[lane];
    float m = -INFINITY, l = 0.f;
    float2 acc = make_float2(0.f, 0.f);
    const float scale = 0.08838834764831845f;     // 1/sqrt(128)

    int p = beg;
    for (; p + 2 <= end; p += 2) {
        int j0 = ssrc[p];
        int j1 = ssrc[p + 1];
        const ushort2* r0 = (const ushort2*)(kv + (size_t)j0 * 256);
        const ushort2* r1 = (const ushort2*)(kv + (size_t)j1 * 256);
        ushort2 ku0 = r0[lane];
        ushort2 vu0 = r0[lane + 64];
        ushort2 ku1 = r1[lane];
        ushort2 vu1 = r1[lane + 64];
        float s0 = q2.x * bf2f(ku0.x) + q2.y * bf2f(ku0.y);
        float s1 = q2.x * bf2f(ku1.x) + q2.y * bf2f(ku1.y);
#pragma unroll
        for (int off = 32; off > 0; off >>= 1) {
            s0 += __shfl_xor(s0, off, 64);
            s1 += __shfl_xor(s1, off, 64);
        }
        s0 *= scale; s1 *= scale;
        float mn = fmaxf(m, fmaxf(s0, s1));
        float ea = __expf(m - mn);
        float e0 = __expf(s0 - mn);
        float e1 = __expf(s1 - mn);
        l = l * ea + e0 + e1;
        acc.x = acc.x * ea + e0 * bf2f(vu0.x) + e1 * bf2f(vu1.x);
        acc.y = acc.y * ea + e0 * bf2f(vu0.y) + e1 * bf2f(vu1.y);
        m = mn;
    }
    if (p < end) {
        int j = ssrc[p];
        const ushort2* r = (const ushort2*)(kv + (size_t)j * 256);
        ushort2 ku = r[lane];
        ushort2 vu = r[lane + 64];
        float s = q2.x * bf2f(ku.x) + q2.y * bf2f(ku.y);
#pragma unroll
        for (int off = 32; off > 0; off >>= 1) s += __shfl_xor(s, off, 64);
        s *= scale;
        float mn = fmaxf(m, s);
        float ea = __expf(m - mn);
        float es = __expf(s - mn);
        l = l * ea + es;
        acc.x = acc.x * ea + es * bf2f(vu.x);
        acc.y = acc.y * ea + es * bf2f(vu.y);
    }
    float inv = 1.f / l;
    float2* o = (float2*)(out + (size_t)node * D_OUT);
    float2 cur = o[lane];
    cur.x += acc.x * inv;
    cur.y += acc.y * inv;
    o[lane] = cur;
}

// ---------------- host launch ----------------
extern "C" void kernel_launch(void* const* d_in, const int* in_sizes, int n_in,
                              void* d_out, int out_size, void* d_ws, size_t ws_size,
                              hipStream_t stream) {
    const float* x     = (const float*)d_in[0];
    const int*   ei    = (const int*)d_in[1];
    const float* W_fc  = (const float*)d_in[2];
    const float* b_fc  = (const float*)d_in[3];
    const float* W_q   = (const float*)d_in[4];
    const float* b_q   = (const float*)d_in[5];
    const float* W_k   = (const float*)d_in[6];
    const float* b_k   = (const float*)d_in[7];
    const float* W_v   = (const float*)d_in[8];
    const float* b_v   = (const float*)d_in[9];
    const float* W_s   = (const float*)d_in[10];
    const float* b_s   = (const float*)d_in[11];
    float* out = (float*)d_out;

    // Workspace: q fp32 (25.6 MB) | kv bf16 interleaved (25.6 MB) | CSR (~3.8 MB)
    // = ~55 MB, well inside ws_size (>= 102.4 MB).
    float* qb = (float*)d_ws;
    unsigned short* kvb = (unsigned short*)(qb + (size_t)N_NODES * D_OUT);
    int* deg    = (int*)(kvb + (size_t)N_NODES * 256);
    int* offs   = deg + N_NODES;          // N+1 entries
    int* cursor = offs + (N_NODES + 1);
    int* bsums  = cursor + N_NODES;
    int* bpref  = bsums + 64;
    int* ssrc   = bpref + 64;             // E entries

    hipMemsetAsync(deg, 0, N_NODES * sizeof(int), stream);

    k_fused<<<NBLK, 256, 0, stream>>>(x, W_fc, b_fc, W_q, b_q, W_k, b_k,
                                      W_v, b_v, W_s, b_s, qb, kvb, out);
    k_deg<<<(E_EDGES + 255) / 256, 256, 0, stream>>>(ei, deg);
    k_scan1<<<NB_SCAN, SCAN_B, 0, stream>>>(deg, offs, bsums);
    k_scan2<<<1, 64, 0, stream>>>(bsums, bpref);
    k_scan3<<<NB_SCAN, SCAN_B, 0, stream>>>(offs, bpref, cursor);
    k_fill<<<(E_EDGES + 255) / 256, 256, 0, stream>>>(ei, cursor, ssrc);
    k_agg<<<(N_NODES + 3) / 4, 256, 0, stream>>>(qb, kvb, offs, ssrc, out);
}

// Round 5
// 319.886 us; speedup vs baseline: 2.1136x; 1.1873x over previous
//
#include <hip/hip_runtime.h>
#include <math.h>

#define N_NODES 50000
#define E_EDGES 800000
#define D_IN    256
#define D_H     128
#define D_OUT   128

#define MT    64                          // nodes per GEMM tile
#define NBLK  ((N_NODES + MT - 1) / MT)   // 782
#define SCAN_B  1024
#define NB_SCAN ((N_NODES + SCAN_B - 1) / SCAN_B)  // 49

typedef __attribute__((ext_vector_type(8))) short bf16x8;
typedef __attribute__((ext_vector_type(4))) float f32x4;

__device__ __forceinline__ unsigned short f2bf(float f) {
    unsigned u = __float_as_uint(f);
    return (unsigned short)((u + 0x7FFFu + ((u >> 16) & 1u)) >> 16);
}
__device__ __forceinline__ float bf2f(unsigned short u) {
    return __uint_as_float((unsigned)u << 16);
}

// Fragment layouts (16x16x32 bf16 MFMA), all verified in R3/R4:
//   A-frag: lane(lm=lane&15, quad=lane>>4) holds A[m=nt*16+lm][k=kblk*32+quad*8 .. +8]
//   B-frag: lane holds W[n=nblk*16+lm][k=kblk*32+quad*8 .. +8]
//   C/D:    col = lane&15, row = quad*4 + reg
// Packed storage: chunk c = (kblk*(N16) + blk)*64 + lane, shorts at c*8 .. +8
// => every wave fragment access is lane-linear 16 B/lane (conflict/coalesce-ideal).

// ---------------- K0: weights fp32 -> bf16, swizzled to B-frag order ------
// wsw layout (shorts): fc[32768] | q[16384] | k[16384] | v[16384] | s[16384]
__global__ __launch_bounds__(256) void k_wconv(const float* __restrict__ Wfc,
                                               const float* __restrict__ Wq,
                                               const float* __restrict__ Wk,
                                               const float* __restrict__ Wv,
                                               const float* __restrict__ Ws,
                                               unsigned short* __restrict__ wsw) {
    int g = blockIdx.x * 256 + threadIdx.x;      // 0..24575 float4 groups
    const float* src; unsigned short* dst; int n, k0;
    if (g < 8192) {                               // W_fc: 128 x 256
        src = Wfc; dst = wsw;
        n = g >> 6; k0 = (g & 63) * 4;
    } else {
        int t = (g - 8192) >> 12;                 // 0..3
        int pos = (g - 8192) & 4095;              // 128 x 128
        src = (t == 0) ? Wq : (t == 1) ? Wk : (t == 2) ? Wv : Ws;
        dst = wsw + 32768 + t * 16384;
        n = pos >> 5; k0 = (pos & 31) * 4;
    }
    float4 v = *(const float4*)(src + (size_t)n * ((g < 8192) ? 256 : 128) + k0);
    unsigned r0 = (unsigned)f2bf(v.x) | ((unsigned)f2bf(v.y) << 16);
    unsigned r1 = (unsigned)f2bf(v.z) | ((unsigned)f2bf(v.w) << 16);
    int kblk = k0 >> 5, quad = (k0 & 31) >> 3, rem = k0 & 7;
    int sidx = (((kblk * 8 + (n >> 4)) * 4 + quad) * 16 + (n & 15)) * 8 + rem;
    *(uint2*)&dst[sidx] = make_uint2(r0, r1);
}

// ---------------- K1: h = relu(x @ W_fc^T + b_fc), packed bf16 out --------
__global__ __launch_bounds__(256) void k_fc(const float* __restrict__ x,
                                            const unsigned short* __restrict__ wfc,
                                            const float* __restrict__ b,
                                            unsigned short* __restrict__ hfrag) {
    __shared__ __align__(16) unsigned short As[MT * D_IN];   // 32 KB, frag-packed
    const int tid  = threadIdx.x;
    const int lane = tid & 63;
    const int wid  = tid >> 6;
    const int lm   = lane & 15;
    const int quad = lane >> 4;
    const int node0 = blockIdx.x * MT;

    // stage x tile (64 x 256 fp32) -> bf16 frag-packed LDS; coalesced reads
#pragma unroll
    for (int i = 0; i < 16; ++i) {
        int idx = tid + i * 256;                 // 0..4095 float4 groups
        int row = idx >> 6;
        int k0  = (idx & 63) * 4;
        int gn  = node0 + row;
        float4 v = make_float4(0.f, 0.f, 0.f, 0.f);
        if (gn < N_NODES) v = *(const float4*)(x + (size_t)gn * D_IN + k0);
        unsigned r0 = (unsigned)f2bf(v.x) | ((unsigned)f2bf(v.y) << 16);
        unsigned r1 = (unsigned)f2bf(v.z) | ((unsigned)f2bf(v.w) << 16);
        int kblk = k0 >> 5, q4 = (k0 & 31) >> 3, rem = k0 & 7;
        int sidx = ((kblk * 4 + (row >> 4)) * 64 + q4 * 16 + (row & 15)) * 8 + rem;
        *(uint2*)&As[sidx] = make_uint2(r0, r1);
    }
    __syncthreads();

    f32x4 acc[4][2];
#pragma unroll
    for (int i = 0; i < 4; ++i)
#pragma unroll
        for (int j = 0; j < 2; ++j) { acc[i][j][0]=0.f; acc[i][j][1]=0.f; acc[i][j][2]=0.f; acc[i][j][3]=0.f; }

#pragma unroll
    for (int kb = 0; kb < 8; ++kb) {             // K = 256
        bf16x8 af[4], bfr[2];
#pragma unroll
        for (int nt = 0; nt < 4; ++nt)
            af[nt] = *(const bf16x8*)&As[(((kb * 4 + nt) * 64) + lane) * 8];
#pragma unroll
        for (int ft = 0; ft < 2; ++ft)
            bfr[ft] = *(const bf16x8*)&wfc[((kb * 8 + wid * 2 + ft) * 64 + lane) * 8];
#pragma unroll
        for (int nt = 0; nt < 4; ++nt)
#pragma unroll
            for (int ft = 0; ft < 2; ++ft)
                acc[nt][ft] = __builtin_amdgcn_mfma_f32_16x16x32_bf16(af[nt], bfr[ft], acc[nt][ft], 0, 0, 0);
    }
    __syncthreads();                              // As dead; reuse for transpose

    // epilogue: bias+relu -> frag-packed h tile via LDS transpose
#pragma unroll
    for (int ft = 0; ft < 2; ++ft) {
        int feat = wid * 32 + ft * 16 + lm;
        float bb = b[feat];
#pragma unroll
        for (int nt = 0; nt < 4; ++nt)
#pragma unroll
            for (int r = 0; r < 4; ++r) {
                float vv = fmaxf(acc[nt][ft][r] + bb, 0.f);
                // h[node=nt*16+quad*4+r][k=feat]: kblk=wid, quad'=ft*2+(lm>>3), j=lm&7
                int sidx = ((wid * 4 + nt) * 64 + (ft * 2 + (lm >> 3)) * 16 + quad * 4 + r) * 8 + (lm & 7);
                As[sidx] = f2bf(vv);
            }
    }
    __syncthreads();
    // copy 16 KB tile to global, fully coalesced
    unsigned short* hdst = hfrag + (size_t)blockIdx.x * 8192;
#pragma unroll
    for (int i = 0; i < 4; ++i) {
        int idx = tid + i * 256;                 // 0..1023 uint4
        *(uint4*)(hdst + idx * 8) = *(const uint4*)&As[idx * 8];
    }
}

// ---------------- K2: q/k/v/skip = h @ W^T + b; NO LDS, no syncs ----------
__global__ __launch_bounds__(256) void k_qkvs(const unsigned short* __restrict__ hfrag,
                                              const unsigned short* __restrict__ wsw,
                                              const float* __restrict__ bq,
                                              const float* __restrict__ bk,
                                              const float* __restrict__ bv,
                                              const float* __restrict__ bs,
                                              float* __restrict__ qo,
                                              unsigned short* __restrict__ kv,
                                              float* __restrict__ out) {
    const int sel = blockIdx.y;
    const unsigned short* W = wsw + 32768 + sel * 16384;
    const float* b = (sel == 0) ? bq : (sel == 1) ? bk : (sel == 2) ? bv : bs;

    const int tid  = threadIdx.x;
    const int lane = tid & 63;
    const int wid  = tid >> 6;
    const int lm   = lane & 15;
    const int quad = lane >> 4;
    const int node0 = blockIdx.x * MT;
    const unsigned short* hsrc = hfrag + (size_t)blockIdx.x * 8192;

    f32x4 acc[4][2];
#pragma unroll
    for (int i = 0; i < 4; ++i)
#pragma unroll
        for (int j = 0; j < 2; ++j) { acc[i][j][0]=0.f; acc[i][j][1]=0.f; acc[i][j][2]=0.f; acc[i][j][3]=0.f; }

#pragma unroll
    for (int kb = 0; kb < 4; ++kb) {             // K = 128
        bf16x8 af[4], bfr[2];
#pragma unroll
        for (int nt = 0; nt < 4; ++nt)
            af[nt] = *(const bf16x8*)&hsrc[((kb * 4 + nt) * 64 + lane) * 8];
#pragma unroll
        for (int ft = 0; ft < 2; ++ft)
            bfr[ft] = *(const bf16x8*)&W[((kb * 8 + wid * 2 + ft) * 64 + lane) * 8];
#pragma unroll
        for (int nt = 0; nt < 4; ++nt)
#pragma unroll
            for (int ft = 0; ft < 2; ++ft)
                acc[nt][ft] = __builtin_amdgcn_mfma_f32_16x16x32_bf16(af[nt], bfr[ft], acc[nt][ft], 0, 0, 0);
    }
#pragma unroll
    for (int ft = 0; ft < 2; ++ft) {
        int feat = wid * 32 + ft * 16 + lm;
        float bb = b[feat];
#pragma unroll
        for (int nt = 0; nt < 4; ++nt)
#pragma unroll
            for (int r = 0; r < 4; ++r) {
                int gn = node0 + nt * 16 + quad * 4 + r;
                if (gn < N_NODES) {
                    float vv = acc[nt][ft][r] + bb;
                    if (sel == 0)      qo[(size_t)gn * D_OUT + feat] = vv;
                    else if (sel == 1) kv[(size_t)gn * 256 + feat] = f2bf(vv);
                    else if (sel == 2) kv[(size_t)gn * 256 + 128 + feat] = f2bf(vv);
                    else               out[(size_t)gn * D_OUT + feat] = vv;
                }
            }
    }
}

// ---------------- CSR build ----------------
__global__ void k_deg(const int* __restrict__ ei, int* __restrict__ deg) {
    int e = blockIdx.x * 256 + threadIdx.x;
    if (e < E_EDGES) atomicAdd(&deg[ei[E_EDGES + e]], 1);
}

__global__ __launch_bounds__(SCAN_B) void k_scan1(const int* __restrict__ deg,
                                                  int* __restrict__ offs,
                                                  int* __restrict__ bsums) {
    __shared__ int s[SCAN_B];
    int tid = threadIdx.x;
    int gid = blockIdx.x * SCAN_B + tid;
    int val = (gid < N_NODES) ? deg[gid] : 0;
    s[tid] = val;
    __syncthreads();
    for (int off = 1; off < SCAN_B; off <<= 1) {
        int t = (tid >= off) ? s[tid - off] : 0;
        __syncthreads();
        s[tid] += t;
        __syncthreads();
    }
    int incl = s[tid];
    if (gid < N_NODES) offs[gid] = incl - val;      // exclusive
    if (tid == SCAN_B - 1) bsums[blockIdx.x] = incl;
}

__global__ void k_scan2(const int* __restrict__ bsums, int* __restrict__ bpref) {
    int lane = threadIdx.x;                       // 64 threads, one wave
    int v = (lane < NB_SCAN) ? bsums[lane] : 0;
    int orig = v;
    for (int off = 1; off < 64; off <<= 1) {
        int t = __shfl_up(v, off, 64);
        if (lane >= off) v += t;
    }
    if (lane < NB_SCAN) bpref[lane] = v - orig;   // exclusive
}

__global__ __launch_bounds__(SCAN_B) void k_scan3(int* __restrict__ offs,
                                                  const int* __restrict__ bpref,
                                                  int* __restrict__ cursor) {
    int gid = blockIdx.x * SCAN_B + threadIdx.x;
    if (gid < N_NODES) {
        int o = offs[gid] + bpref[blockIdx.x];
        offs[gid] = o;
        cursor[gid] = o;
    }
    if (gid == 0) offs[N_NODES] = E_EDGES;
}

__global__ void k_fill(const int* __restrict__ ei, int* __restrict__ cursor,
                       int* __restrict__ ssrc) {
    int e = blockIdx.x * 256 + threadIdx.x;
    if (e < E_EDGES) {
        int d = ei[E_EDGES + e];
        int p = atomicAdd(&cursor[d], 1);
        ssrc[p] = ei[e];
    }
}

// ---------------- K6: per-node online-softmax aggregation (bf16 kv) -------
__global__ __launch_bounds__(256) void k_agg(const float* __restrict__ q,
                                             const unsigned short* __restrict__ kv,
                                             const int* __restrict__ offs,
                                             const int* __restrict__ ssrc,
                                             float* __restrict__ out) {
    const int wave = threadIdx.x >> 6;
    const int lane = threadIdx.x & 63;
    const int node = blockIdx.x * 4 + wave;
    if (node >= N_NODES) return;
    const int beg = offs[node];
    const int end = offs[node + 1];
    if (beg == end) return;                       // out already holds skip

    float2 q2 = ((const float2*)(q + (size_t)node * D_OUT))[lane];
    float m = -INFINITY, l = 0.f;
    float2 acc = make_float2(0.f, 0.f);
    const float scale = 0.08838834764831845f;     // 1/sqrt(128)

    int p = beg;
    for (; p + 2 <= end; p += 2) {
        int j0 = ssrc[p];
        int j1 = ssrc[p + 1];
        const ushort2* r0 = (const ushort2*)(kv + (size_t)j0 * 256);
        const ushort2* r1 = (const ushort2*)(kv + (size_t)j1 * 256);
        ushort2 ku0 = r0[lane];
        ushort2 vu0 = r0[lane + 64];
        ushort2 ku1 = r1[lane];
        ushort2 vu1 = r1[lane + 64];
        float s0 = q2.x * bf2f(ku0.x) + q2.y * bf2f(ku0.y);
        float s1 = q2.x * bf2f(ku1.x) + q2.y * bf2f(ku1.y);
#pragma unroll
        for (int off = 32; off > 0; off >>= 1) {
            s0 += __shfl_xor(s0, off, 64);
            s1 += __shfl_xor(s1, off, 64);
        }
        s0 *= scale; s1 *= scale;
        float mn = fmaxf(m, fmaxf(s0, s1));
        float ea = __expf(m - mn);
        float e0 = __expf(s0 - mn);
        float e1 = __expf(s1 - mn);
        l = l * ea + e0 + e1;
        acc.x = acc.x * ea + e0 * bf2f(vu0.x) + e1 * bf2f(vu1.x);
        acc.y = acc.y * ea + e0 * bf2f(vu0.y) + e1 * bf2f(vu1.y);
        m = mn;
    }
    if (p < end) {
        int j = ssrc[p];
        const ushort2* r = (const ushort2*)(kv + (size_t)j * 256);
        ushort2 ku = r[lane];
        ushort2 vu = r[lane + 64];
        float s = q2.x * bf2f(ku.x) + q2.y * bf2f(ku.y);
#pragma unroll
        for (int off = 32; off > 0; off >>= 1) s += __shfl_xor(s, off, 64);
        s *= scale;
        float mn = fmaxf(m, s);
        float ea = __expf(m - mn);
        float es = __expf(s - mn);
        l = l * ea + es;
        acc.x = acc.x * ea + es * bf2f(vu.x);
        acc.y = acc.y * ea + es * bf2f(vu.y);
    }
    float inv = 1.f / l;
    float2* o = (float2*)(out + (size_t)node * D_OUT);
    float2 cur = o[lane];
    cur.x += acc.x * inv;
    cur.y += acc.y * inv;
    o[lane] = cur;
}

// ---------------- host launch ----------------
extern "C" void kernel_launch(void* const* d_in, const int* in_sizes, int n_in,
                              void* d_out, int out_size, void* d_ws, size_t ws_size,
                              hipStream_t stream) {
    const float* x     = (const float*)d_in[0];
    const int*   ei    = (const int*)d_in[1];
    const float* W_fc  = (const float*)d_in[2];
    const float* b_fc  = (const float*)d_in[3];
    const float* W_q   = (const float*)d_in[4];
    const float* b_q   = (const float*)d_in[5];
    const float* W_k   = (const float*)d_in[6];
    const float* b_k   = (const float*)d_in[7];
    const float* W_v   = (const float*)d_in[8];
    const float* b_v   = (const float*)d_in[9];
    const float* W_s   = (const float*)d_in[10];
    const float* b_s   = (const float*)d_in[11];
    float* out = (float*)d_out;

    // ws layout: q fp32 25.6MB | kv bf16 25.6MB | hfrag bf16 12.8MB |
    //            wsw bf16 196KB | CSR ~3.8MB  => ~68 MB total (< ws_size)
    float* qb = (float*)d_ws;
    unsigned short* kvb   = (unsigned short*)(qb + (size_t)N_NODES * D_OUT);
    unsigned short* hfrag = kvb + (size_t)N_NODES * 256;
    unsigned short* wsw   = hfrag + (size_t)NBLK * 8192;
    int* deg    = (int*)(wsw + 98304);
    int* offs   = deg + N_NODES;          // N+1 entries
    int* cursor = offs + (N_NODES + 1);
    int* bsums  = cursor + N_NODES;
    int* bpref  = bsums + 64;
    int* ssrc   = bpref + 64;             // E entries

    hipMemsetAsync(deg, 0, N_NODES * sizeof(int), stream);

    k_wconv<<<96, 256, 0, stream>>>(W_fc, W_q, W_k, W_v, W_s, wsw);
    k_fc<<<NBLK, 256, 0, stream>>>(x, wsw, b_fc, hfrag);
    k_qkvs<<<dim3(NBLK, 4), 256, 0, stream>>>(hfrag, wsw, b_q, b_k, b_v, b_s,
                                              qb, kvb, out);
    k_deg<<<(E_EDGES + 255) / 256, 256, 0, stream>>>(ei, deg);
    k_scan1<<<NB_SCAN, SCAN_B, 0, stream>>>(deg, offs, bsums);
    k_scan2<<<1, 64, 0, stream>>>(bsums, bpref);
    k_scan3<<<NB_SCAN, SCAN_B, 0, stream>>>(offs, bpref, cursor);
    k_fill<<<(E_EDGES + 255) / 256, 256, 0, stream>>>(ei, cursor, ssrc);
    k_agg<<<(N_NODES + 3) / 4, 256, 0, stream>>>(qb, kvb, offs, ssrc, out);
}